// Round 1
// baseline (106.652 us; speedup 1.0000x reference)
//
#include <hip/hip_runtime.h>
#include <math.h>

#define N_ 2
#define C_ 32
#define X_ 48
#define Y_ 48
#define Z_ 24
#define M_ (X_*Y_*Z_)   // 55296
#define NM_ (N_*M_)     // 110592

__global__ __launch_bounds__(256) void norms_kernel(
    const float* __restrict__ f0, const float* __restrict__ f1,
    const float* __restrict__ logit_scale,
    float* __restrict__ rn0s, float* __restrict__ rn1)
{
    int t = blockIdx.x * blockDim.x + threadIdx.x;
    if (t >= NM_) return;
    int n = t / M_;
    int m = t - n * M_;
    const float* p0 = f0 + (size_t)n * C_ * M_ + m;
    const float* p1 = f1 + (size_t)n * C_ * M_ + m;
    float s0 = 0.f, s1 = 0.f;
#pragma unroll
    for (int c = 0; c < C_; ++c) {
        float a = p0[(size_t)c * M_];
        float b = p1[(size_t)c * M_];
        s0 = fmaf(a, a, s0);
        s1 = fmaf(b, b, s1);
    }
    float scale = __expf(logit_scale[0]);
    rn0s[t] = scale / (sqrtf(s0) + 1e-7f);
    rn1[t]  = 1.0f  / (sqrtf(s1) + 1e-7f);
}

__global__ __launch_bounds__(256) void track_kernel(
    const float* __restrict__ f0, const float* __restrict__ f1,
    const float* __restrict__ rn0s, const float* __restrict__ rn1,
    float* __restrict__ out)
{
    int t = blockIdx.x * blockDim.x + threadIdx.x;
    if (t >= NM_) return;
    int n = t / M_;
    int m = t - n * M_;
    int x = m / (Y_ * Z_);
    int r = m - x * (Y_ * Z_);
    int y = r / Z_;
    int z = r - y * Z_;

    int vofs[27];
    unsigned valid = 0u;
#pragma unroll
    for (int o = 0; o < 27; ++o) {
        const int dx = o / 9 - 1, dy = (o / 3) % 3 - 1, dz = o % 3 - 1;
        int xi = x + dx, yi = y + dy, zi = z + dz;
        bool v = (xi >= 0) & (xi < X_) & (yi >= 0) & (yi < Y_) & (zi >= 0) & (zi < Z_);
        valid |= ((unsigned)v) << o;
        int xc = min(max(xi, 0), X_ - 1);
        int yc = min(max(yi, 0), Y_ - 1);
        int zc = min(max(zi, 0), Z_ - 1);
        vofs[o] = (xc * Y_ + yc) * Z_ + zc;
    }

    float acc[27];
#pragma unroll
    for (int o = 0; o < 27; ++o) acc[o] = 0.f;

    const float* p0 = f0 + (size_t)n * C_ * M_ + m;
    const float* p1 = f1 + (size_t)n * C_ * M_;
    for (int c = 0; c < C_; ++c) {
        float a = p0[(size_t)c * M_];
        const float* pc = p1 + (size_t)c * M_;
#pragma unroll
        for (int o = 0; o < 27; ++o)
            acc[o] = fmaf(a, pc[vofs[o]], acc[o]);
    }

    float rs = rn0s[t];
    const float* rnb = rn1 + n * M_;
    float logit[27];
#pragma unroll
    for (int o = 0; o < 27; ++o) {
        float l = acc[o] * rs * rnb[vofs[o]];
        logit[o] = ((valid >> o) & 1u) ? l : 0.0f;
    }

    float mx = logit[0];
#pragma unroll
    for (int o = 1; o < 27; ++o) mx = fmaxf(mx, logit[o]);

    float s = 0.f, fx = 0.f, fy = 0.f, fz = 0.f;
#pragma unroll
    for (int o = 0; o < 27; ++o) {
        float e = __expf(logit[o] - mx);
        s += e;
        fx += e * (float)(o / 9 - 1);
        fy += e * (float)((o / 3) % 3 - 1);
        fz += e * (float)(o % 3 - 1);
    }
    float inv = 1.0f / s;
    size_t ob = (size_t)t * 3;
    out[ob + 0] = fx * inv;
    out[ob + 1] = fy * inv;
    out[ob + 2] = fz * inv;
}

extern "C" void kernel_launch(void* const* d_in, const int* in_sizes, int n_in,
                              void* d_out, int out_size, void* d_ws, size_t ws_size,
                              hipStream_t stream) {
    const float* f0 = (const float*)d_in[0];
    const float* f1 = (const float*)d_in[1];
    // d_in[2] = spatial_locations (implicit meshgrid, re-derived on device)
    const float* ls = (const float*)d_in[3];
    // d_in[4] = training (fixed to 1 by setup_inputs; training path implemented)

    float* rn0s = (float*)d_ws;            // NM_ floats: exp(ls)/(||f0||+eps)
    float* rn1  = rn0s + NM_;              // NM_ floats: 1/(||f1||+eps)
    float* out  = (float*)d_out;

    const int threads = 256;
    const int blocks = (NM_ + threads - 1) / threads;   // 432
    norms_kernel<<<blocks, threads, 0, stream>>>(f0, f1, ls, rn0s, rn1);
    track_kernel<<<blocks, threads, 0, stream>>>(f0, f1, rn0s, rn1, out);
}

// Round 2
// 32.738 us; speedup vs baseline: 3.2578x; 3.2578x over previous
//
#include <hip/hip_runtime.h>
#include <math.h>

#define N_ 2
#define C_ 32
#define X_ 48
#define Y_ 48
#define Z_ 24
#define M_ (X_*Y_*Z_)   // 55296
#define NM_ (N_*M_)     // 110592

typedef _Float16 h2 __attribute__((ext_vector_type(2)));

#if __has_builtin(__builtin_amdgcn_fdot2)
__device__ __forceinline__ float dot2(h2 a, h2 b, float c) {
    return __builtin_amdgcn_fdot2(a, b, c, false);
}
#else
__device__ __forceinline__ float dot2(h2 a, h2 b, float c) {
    return fmaf((float)a[1], (float)b[1], fmaf((float)a[0], (float)b[0], c));
}
#endif

// Per voxel: L2-normalize f0 (folding in exp(logit_scale)) and f1, convert to
// fp16, store voxel-major (32 contiguous halves = 64 B per voxel).
__global__ __launch_bounds__(256) void prep_kernel(
    const float* __restrict__ f0, const float* __restrict__ f1,
    const float* __restrict__ logit_scale,
    h2* __restrict__ f0n, h2* __restrict__ f1n)
{
    int t = blockIdx.x * blockDim.x + threadIdx.x;
    if (t >= NM_) return;
    int n = t / M_;
    int m = t - n * M_;
    const float* p0 = f0 + (size_t)n * C_ * M_ + m;
    const float* p1 = f1 + (size_t)n * C_ * M_ + m;
    float a[C_], b[C_];
    float s0 = 0.f, s1 = 0.f;
#pragma unroll
    for (int c = 0; c < C_; ++c) {
        a[c] = p0[(size_t)c * M_];
        s0 = fmaf(a[c], a[c], s0);
    }
#pragma unroll
    for (int c = 0; c < C_; ++c) {
        b[c] = p1[(size_t)c * M_];
        s1 = fmaf(b[c], b[c], s1);
    }
    float rs0 = __expf(logit_scale[0]) / (sqrtf(s0) + 1e-7f);
    float rs1 = 1.0f / (sqrtf(s1) + 1e-7f);

    union { int4 q[4]; h2 h[16]; } u0, u1;
#pragma unroll
    for (int i = 0; i < 16; ++i) {
        h2 v0, v1;
        v0[0] = (_Float16)(a[2*i]   * rs0);
        v0[1] = (_Float16)(a[2*i+1] * rs0);
        v1[0] = (_Float16)(b[2*i]   * rs1);
        v1[1] = (_Float16)(b[2*i+1] * rs1);
        u0.h[i] = v0;
        u1.h[i] = v1;
    }
    int4* q0 = (int4*)(f0n + (size_t)t * 16);
    int4* q1 = (int4*)(f1n + (size_t)t * 16);
#pragma unroll
    for (int j = 0; j < 4; ++j) { q0[j] = u0.q[j]; q1[j] = u1.q[j]; }
}

// Lane layout: lanes 0-31 handle channels 0-15 of 32 consecutive voxels,
// lanes 32-63 handle channels 16-31 of the same voxels. Halves combined with
// one shfl_xor(32) per offset. 2x the waves of a thread-per-voxel layout.
__global__ __launch_bounds__(256) void track_kernel(
    const h2* __restrict__ f0n, const h2* __restrict__ f1n,
    float* __restrict__ out)
{
    int t = blockIdx.x * 256 + threadIdx.x;
    int lane = threadIdx.x & 63;
    int hi = lane >> 5;                    // channel half
    int vox = (t >> 6) * 32 + (lane & 31); // global voxel, 32 per wave
    int n = vox / M_;
    int m = vox - n * M_;
    int x = m / (Y_ * Z_);
    int r = m - x * (Y_ * Z_);
    int y = r / Z_;
    int z = r - y * Z_;

    // own-channel f0 chunk (16 halves = 32 B)
    union { int4 q[2]; h2 h[8]; } A;
    {
        const int4* p = (const int4*)(f0n + ((size_t)vox * 16 + hi * 8));
        A.q[0] = p[0];
        A.q[1] = p[1];
    }

    int vofs[27];
    unsigned valid = 0u;
#pragma unroll
    for (int o = 0; o < 27; ++o) {
        const int dx = o / 9 - 1, dy = (o / 3) % 3 - 1, dz = o % 3 - 1;
        int xi = x + dx, yi = y + dy, zi = z + dz;
        bool v = (xi >= 0) & (xi < X_) & (yi >= 0) & (yi < Y_) & (zi >= 0) & (zi < Z_);
        valid |= ((unsigned)v) << o;
        int xc = min(max(xi, 0), X_ - 1);
        int yc = min(max(yi, 0), Y_ - 1);
        int zc = min(max(zi, 0), Z_ - 1);
        vofs[o] = (xc * Y_ + yc) * Z_ + zc;
    }

    const h2* base1 = f1n + (size_t)n * M_ * 16 + (size_t)hi * 8;
    float acc[27];
#pragma unroll
    for (int o = 0; o < 27; ++o) {
        union { int4 q[2]; h2 h[8]; } B;
        const int4* p = (const int4*)(base1 + (size_t)vofs[o] * 16);
        B.q[0] = p[0];
        B.q[1] = p[1];
        float s = 0.f;
#pragma unroll
        for (int j = 0; j < 8; ++j) s = dot2(A.h[j], B.h[j], s);
        acc[o] = s;
    }

    // combine channel halves: both halves end with the full dot
#pragma unroll
    for (int o = 0; o < 27; ++o) acc[o] += __shfl_xor(acc[o], 32, 64);

#pragma unroll
    for (int o = 0; o < 27; ++o) acc[o] = ((valid >> o) & 1u) ? acc[o] : 0.0f;

    float mx = acc[0];
#pragma unroll
    for (int o = 1; o < 27; ++o) mx = fmaxf(mx, acc[o]);

    float s = 0.f, fx = 0.f, fy = 0.f, fz = 0.f;
#pragma unroll
    for (int o = 0; o < 27; ++o) {
        float e = __expf(acc[o] - mx);
        s += e;
        fx += e * (float)(o / 9 - 1);
        fy += e * (float)((o / 3) % 3 - 1);
        fz += e * (float)(o % 3 - 1);
    }
    float inv = 1.0f / s;
    if (hi == 0) {
        size_t ob = (size_t)vox * 3;
        out[ob + 0] = fx * inv;
        out[ob + 1] = fy * inv;
        out[ob + 2] = fz * inv;
    }
}

extern "C" void kernel_launch(void* const* d_in, const int* in_sizes, int n_in,
                              void* d_out, int out_size, void* d_ws, size_t ws_size,
                              hipStream_t stream) {
    const float* f0 = (const float*)d_in[0];
    const float* f1 = (const float*)d_in[1];
    const float* ls = (const float*)d_in[3];

    h2* f0n = (h2*)d_ws;                 // NM_*16 h2 = 7.08 MB
    h2* f1n = f0n + (size_t)NM_ * 16;    // 7.08 MB
    float* out = (float*)d_out;

    prep_kernel<<<(NM_ + 255) / 256, 256, 0, stream>>>(f0, f1, ls, f0n, f1n);
    track_kernel<<<(NM_ * 2) / 256, 256, 0, stream>>>(f0n, f1n, out);
}

// Round 3
// 29.318 us; speedup vs baseline: 3.6378x; 1.1166x over previous
//
#include <hip/hip_runtime.h>
#include <math.h>

#define N_ 2
#define C_ 32
#define X_ 48
#define Y_ 48
#define Z_ 24
#define M_ (X_*Y_*Z_)   // 55296
#define NM_ (N_*M_)     // 110592

typedef _Float16 h2 __attribute__((ext_vector_type(2)));

#if __has_builtin(__builtin_amdgcn_fdot2)
__device__ __forceinline__ float dot2(h2 a, h2 b, float c) {
    return __builtin_amdgcn_fdot2(a, b, c, false);
}
#else
__device__ __forceinline__ float dot2(h2 a, h2 b, float c) {
    return fmaf((float)a[1], (float)b[1], fmaf((float)a[0], (float)b[0], c));
}
#endif

// f1 -> normalized fp16, voxel-major (32 contiguous halves = 64 B per voxel).
// 2 threads per voxel: lane&31 = voxel slot, lane>>5 = channel half.
__global__ __launch_bounds__(256) void prep_f1(
    const float* __restrict__ f1, h2* __restrict__ f1n)
{
    int t = blockIdx.x * 256 + threadIdx.x;      // [0, NM_*2)
    int lane = threadIdx.x & 63;
    int hi = lane >> 5;
    int vox = (t >> 6) * 32 + (lane & 31);
    int n = vox / M_;
    int m = vox - n * M_;

    const float* p = f1 + (size_t)n * C_ * M_ + (size_t)hi * 16 * M_ + m;
    float b[16];
    float s = 0.f;
#pragma unroll
    for (int i = 0; i < 16; ++i) {
        b[i] = p[(size_t)i * M_];
        s = fmaf(b[i], b[i], s);
    }
    s += __shfl_xor(s, 32, 64);                  // other half, same voxel
    float rs = 1.0f / (sqrtf(s) + 1e-7f);

    union { int4 q[2]; h2 h[8]; } u;
#pragma unroll
    for (int i = 0; i < 8; ++i) {
        h2 v;
        v[0] = (_Float16)(b[2*i]   * rs);
        v[1] = (_Float16)(b[2*i+1] * rs);
        u.h[i] = v;
    }
    int4* q = (int4*)(f1n + (size_t)vox * 16 + hi * 8);
    q[0] = u.q[0];
    q[1] = u.q[1];
}

// 4 threads per voxel: lane&15 = voxel slot (z-consecutive), lane>>4 = channel
// quarter (8 channels). f0 read raw + normalized on the fly (norm via 2
// shfl_xor); f1 neighbors gathered as one dwordx4 per offset.
__global__ __launch_bounds__(256) void track_kernel(
    const float* __restrict__ f0, const float* __restrict__ logit_scale,
    const h2* __restrict__ f1n, float* __restrict__ out)
{
    int t = blockIdx.x * 256 + threadIdx.x;      // [0, NM_*4)
    int lane = threadIdx.x & 63;
    int q4 = lane >> 4;
    int vox = (t >> 6) * 16 + (lane & 15);
    int n = vox / M_;
    int m = vox - n * M_;
    int x = m / (Y_ * Z_);
    int r = m - x * (Y_ * Z_);
    int y = r / Z_;
    int z = r - y * Z_;

    // own 8 channels of raw f0, cross-quarter norm reduce
    const float* p0 = f0 + (size_t)n * C_ * M_ + (size_t)q4 * 8 * M_ + m;
    float a[8];
    float s0 = 0.f;
#pragma unroll
    for (int i = 0; i < 8; ++i) {
        a[i] = p0[(size_t)i * M_];
        s0 = fmaf(a[i], a[i], s0);
    }
    s0 += __shfl_xor(s0, 16, 64);
    s0 += __shfl_xor(s0, 32, 64);
    float rs0 = __expf(logit_scale[0]) / (sqrtf(s0) + 1e-7f);
    h2 A[4];
#pragma unroll
    for (int i = 0; i < 4; ++i) {
        h2 v;
        v[0] = (_Float16)(a[2*i]   * rs0);
        v[1] = (_Float16)(a[2*i+1] * rs0);
        A[i] = v;
    }

    // clamped per-axis coords + per-axis validity bits
    int xs[3], ys[3], zs[3];
    unsigned vxm = 0, vym = 0, vzm = 0;
#pragma unroll
    for (int d = 0; d < 3; ++d) {
        int xi = x + d - 1, yi = y + d - 1, zi = z + d - 1;
        vxm |= ((unsigned)(xi >= 0 && xi < X_)) << d;
        vym |= ((unsigned)(yi >= 0 && yi < Y_)) << d;
        vzm |= ((unsigned)(zi >= 0 && zi < Z_)) << d;
        xs[d] = min(max(xi, 0), X_ - 1);
        ys[d] = min(max(yi, 0), Y_ - 1);
        zs[d] = min(max(zi, 0), Z_ - 1);
    }

    const h2* base1 = f1n + (size_t)n * M_ * 16 + q4 * 4;
    float acc[27];
    unsigned valid = 0;
#pragma unroll
    for (int i = 0; i < 3; ++i)
#pragma unroll
    for (int j = 0; j < 3; ++j)
#pragma unroll
    for (int k = 0; k < 3; ++k) {
        int o = (i * 3 + j) * 3 + k;
        valid |= (((vxm >> i) & (vym >> j) & (vzm >> k)) & 1u) << o;
        int voff = (xs[i] * Y_ + ys[j]) * Z_ + zs[k];
        union { int4 qq; h2 h[4]; } B;
        B.qq = *(const int4*)(base1 + (size_t)voff * 16);
        float s = 0.f;
#pragma unroll
        for (int u = 0; u < 4; ++u) s = dot2(A[u], B.h[u], s);
        acc[o] = s;
    }

    // cross-quarter sum: full 32-channel dot in every lane
#pragma unroll
    for (int o = 0; o < 27; ++o) {
        acc[o] += __shfl_xor(acc[o], 16, 64);
        acc[o] += __shfl_xor(acc[o], 32, 64);
    }

#pragma unroll
    for (int o = 0; o < 27; ++o)
        acc[o] = ((valid >> o) & 1u) ? acc[o] : 0.0f;

    float mx = acc[0];
#pragma unroll
    for (int o = 1; o < 27; ++o) mx = fmaxf(mx, acc[o]);

    float s = 0.f, fx = 0.f, fy = 0.f, fz = 0.f;
#pragma unroll
    for (int o = 0; o < 27; ++o) {
        float e = __expf(acc[o] - mx);
        s += e;
        fx += e * (float)(o / 9 - 1);
        fy += e * (float)((o / 3) % 3 - 1);
        fz += e * (float)(o % 3 - 1);
    }
    float inv = 1.0f / s;
    if (q4 == 0) {
        size_t ob = (size_t)vox * 3;
        out[ob + 0] = fx * inv;
        out[ob + 1] = fy * inv;
        out[ob + 2] = fz * inv;
    }
}

extern "C" void kernel_launch(void* const* d_in, const int* in_sizes, int n_in,
                              void* d_out, int out_size, void* d_ws, size_t ws_size,
                              hipStream_t stream) {
    const float* f0 = (const float*)d_in[0];
    const float* f1 = (const float*)d_in[1];
    const float* ls = (const float*)d_in[3];

    h2* f1n = (h2*)d_ws;                 // NM_*16 h2 = 7.08 MB
    float* out = (float*)d_out;

    prep_f1<<<(NM_ * 2) / 256, 256, 0, stream>>>(f1, f1n);
    track_kernel<<<(NM_ * 4) / 256, 256, 0, stream>>>(f0, ls, f1n, out);
}

// Round 4
// 29.170 us; speedup vs baseline: 3.6563x; 1.0051x over previous
//
#include <hip/hip_runtime.h>
#include <math.h>

#define N_ 2
#define C_ 32
#define X_ 48
#define Y_ 48
#define Z_ 24
#define M_ (X_*Y_*Z_)   // 55296
#define NM_ (N_*M_)     // 110592

typedef _Float16 h2 __attribute__((ext_vector_type(2)));

#if __has_builtin(__builtin_amdgcn_fdot2)
__device__ __forceinline__ float dot2(h2 a, h2 b, float c) {
    return __builtin_amdgcn_fdot2(a, b, c, false);
}
#else
__device__ __forceinline__ float dot2(h2 a, h2 b, float c) {
    return fmaf((float)a[1], (float)b[1], fmaf((float)a[0], (float)b[0], c));
}
#endif

// f1 -> normalized fp16, voxel-major (32 contiguous halves = 64 B per voxel).
// 4 threads/voxel: lane&15 = voxel slot, lane>>4 = channel quarter (8 ch).
// 1728 blocks -> 27 waves/CU; 8 coalesced loads/thread.
__global__ __launch_bounds__(256) void prep_f1(
    const float* __restrict__ f1, h2* __restrict__ f1n)
{
    int t = blockIdx.x * 256 + threadIdx.x;      // [0, NM_*4)
    int lane = threadIdx.x & 63;
    int q = lane >> 4;
    int vox = (t >> 6) * 16 + (lane & 15);
    int n = vox / M_;
    int m = vox - n * M_;

    const float* p = f1 + (size_t)n * C_ * M_ + (size_t)q * 8 * M_ + m;
    float b[8];
    float s = 0.f;
#pragma unroll
    for (int i = 0; i < 8; ++i) {
        b[i] = p[(size_t)i * M_];
        s = fmaf(b[i], b[i], s);
    }
    s += __shfl_xor(s, 16, 64);
    s += __shfl_xor(s, 32, 64);
    float rs = 1.0f / (sqrtf(s) + 1e-7f);

    union { int4 q4; h2 h[4]; } u;
#pragma unroll
    for (int i = 0; i < 4; ++i) {
        h2 v;
        v[0] = (_Float16)(b[2*i]   * rs);
        v[1] = (_Float16)(b[2*i+1] * rs);
        u.h[i] = v;
    }
    *(int4*)(f1n + (size_t)vox * 16 + q * 4) = u.q4;
}

// 2 threads/voxel: lane&31 = voxel slot, lane>>5 = channel half (16 ch).
// Online no-max softmax (logits bounded by +-exp(logit_scale)=14.29, exp fits
// fp32) -> only {S,FX,FY,FZ} accumulators live, VGPR <= 64 target.
// Per offset: 2x dwordx4 gather + 8 dot2 + 1 shfl_xor + 1 exp.
__global__ __launch_bounds__(256) void track_kernel(
    const float* __restrict__ f0, const float* __restrict__ logit_scale,
    const h2* __restrict__ f1n, float* __restrict__ out)
{
    int t = blockIdx.x * 256 + threadIdx.x;      // [0, NM_*2)
    int lane = threadIdx.x & 63;
    int hi = lane >> 5;
    int vox = (t >> 6) * 32 + (lane & 31);
    int n = vox / M_;
    int m = vox - n * M_;
    int x = m / (Y_ * Z_);
    int r = m - x * (Y_ * Z_);
    int y = r / Z_;
    int z = r - y * Z_;

    // own 16 channels of raw f0, cross-half norm reduce
    const float* p0 = f0 + (size_t)n * C_ * M_ + (size_t)hi * 16 * M_ + m;
    float a[16];
    float s0 = 0.f;
#pragma unroll
    for (int i = 0; i < 16; ++i) {
        a[i] = p0[(size_t)i * M_];
        s0 = fmaf(a[i], a[i], s0);
    }
    s0 += __shfl_xor(s0, 32, 64);
    float rs0 = __expf(logit_scale[0]) / (sqrtf(s0) + 1e-7f);
    h2 A[8];
#pragma unroll
    for (int i = 0; i < 8; ++i) {
        h2 v;
        v[0] = (_Float16)(a[2*i]   * rs0);
        v[1] = (_Float16)(a[2*i+1] * rs0);
        A[i] = v;
    }

    // clamped per-axis coords + validity
    int xs[3], ys[3], zs[3];
    bool vx[3], vy[3], vz[3];
#pragma unroll
    for (int d = 0; d < 3; ++d) {
        int xi = x + d - 1, yi = y + d - 1, zi = z + d - 1;
        vx[d] = (xi >= 0) & (xi < X_);
        vy[d] = (yi >= 0) & (yi < Y_);
        vz[d] = (zi >= 0) & (zi < Z_);
        xs[d] = min(max(xi, 0), X_ - 1);
        ys[d] = min(max(yi, 0), Y_ - 1);
        zs[d] = min(max(zi, 0), Z_ - 1);
    }

    const h2* base1 = f1n + (size_t)n * M_ * 16 + hi * 8;
    float S = 0.f, FX = 0.f, FY = 0.f, FZ = 0.f;
#pragma unroll
    for (int i = 0; i < 3; ++i)
#pragma unroll
    for (int j = 0; j < 3; ++j)
#pragma unroll
    for (int k = 0; k < 3; ++k) {
        bool val = vx[i] & vy[j] & vz[k];
        int voff = (xs[i] * Y_ + ys[j]) * Z_ + zs[k];
        union { int4 qq[2]; h2 h[8]; } B;
        const int4* p = (const int4*)(base1 + (size_t)voff * 16);
        B.qq[0] = p[0];
        B.qq[1] = p[1];
        float d = 0.f;
#pragma unroll
        for (int u = 0; u < 8; ++u) d = dot2(A[u], B.h[u], d);
        d += __shfl_xor(d, 32, 64);          // full 32-channel dot
        d = val ? d : 0.0f;                  // invalid -> logit 0 (e = 1)
        float e = __expf(d);
        S += e;
        if (i == 0) FX -= e; else if (i == 2) FX += e;
        if (j == 0) FY -= e; else if (j == 2) FY += e;
        if (k == 0) FZ -= e; else if (k == 2) FZ += e;
    }

    float inv = 1.0f / S;
    if (hi == 0) {
        size_t ob = (size_t)vox * 3;
        out[ob + 0] = FX * inv;
        out[ob + 1] = FY * inv;
        out[ob + 2] = FZ * inv;
    }
}

extern "C" void kernel_launch(void* const* d_in, const int* in_sizes, int n_in,
                              void* d_out, int out_size, void* d_ws, size_t ws_size,
                              hipStream_t stream) {
    const float* f0 = (const float*)d_in[0];
    const float* f1 = (const float*)d_in[1];
    const float* ls = (const float*)d_in[3];

    h2* f1n = (h2*)d_ws;                 // NM_*16 h2 = 7.08 MB
    float* out = (float*)d_out;

    prep_f1<<<(NM_ * 4) / 256, 256, 0, stream>>>(f1, f1n);
    track_kernel<<<(NM_ * 2) / 256, 256, 0, stream>>>(f0, ls, f1n, out);
}

// Round 5
// 18.242 us; speedup vs baseline: 5.8466x; 1.5991x over previous
//
#include <hip/hip_runtime.h>
#include <math.h>

#define N_ 2
#define C_ 32
#define X_ 48
#define Y_ 48
#define Z_ 24
#define M_ (X_*Y_*Z_)   // 55296
#define NM_ (N_*M_)     // 110592

#define TX_ 2
#define TY_ 4
#define HX_ (TX_+2)          // 4
#define HY_ (TY_+2)          // 6
#define HVOX_ (HX_*HY_*Z_)   // 576 halo voxels
#define TVOX_ (TX_*TY_*Z_)   // 192 output voxels
#define THREADS_ 384         // 2 threads per output voxel (channel halves)
#define NXT_ (X_/TX_)        // 24
#define NYT_ (Y_/TY_)        // 12

typedef _Float16 h2 __attribute__((ext_vector_type(2)));

#if __has_builtin(__builtin_amdgcn_fdot2)
__device__ __forceinline__ float dot2(h2 a, h2 b, float c) {
    return __builtin_amdgcn_fdot2(a, b, c, false);
}
#else
__device__ __forceinline__ float dot2(h2 a, h2 b, float c) {
    return fmaf((float)a[1], (float)b[1], fmaf((float)a[0], (float)b[0], c));
}
#endif

// Single fused kernel. Per block:
//  Phase 1: load raw f1 halo (HX_*HY_*24 voxels, clamped coords), L2-normalize,
//           store fp16 voxel-major in LDS with XOR-swizzled 16B quads.
//  Phase 2: per output voxel (2 threads = channel halves): normalize f0 on the
//           fly (fold exp(logit_scale)), 27 neighbor dots from LDS, online
//           no-max softmax (logits bounded by exp(logit_scale)=14.29).
__global__ __launch_bounds__(THREADS_, 3) void fused_kernel(
    const float* __restrict__ f0, const float* __restrict__ f1,
    const float* __restrict__ logit_scale, float* __restrict__ out)
{
    __shared__ int4 lds[HVOX_ * 4];   // 36,864 B

    const int tid = threadIdx.x;
    const int bid = blockIdx.x;
    const int n   = bid / (NXT_ * NYT_);
    const int rem = bid - n * (NXT_ * NYT_);
    const int xt  = rem % NXT_;
    const int yt  = rem / NXT_;
    const int x0  = xt * TX_;
    const int y0  = yt * TY_;

    // ---------------- Phase 1: f1 halo -> normalized fp16 in LDS ----------
    const float* f1b = f1 + (size_t)n * C_ * M_;
    for (int h = tid; h < HVOX_; h += THREADS_) {
        int hx = h / (HY_ * Z_);
        int rh = h - hx * (HY_ * Z_);
        int hy = rh / Z_;
        int hz = rh - hy * Z_;
        int gx = min(max(x0 - 1 + hx, 0), X_ - 1);
        int gy = min(max(y0 - 1 + hy, 0), Y_ - 1);
        int gm = (gx * Y_ + gy) * Z_ + hz;

        float b[C_];
        float s = 0.f;
#pragma unroll
        for (int c = 0; c < C_; ++c) {
            b[c] = f1b[(size_t)c * M_ + gm];
            s = fmaf(b[c], b[c], s);
        }
        float rs = 1.0f / (sqrtf(s) + 1e-7f);
#pragma unroll
        for (int q = 0; q < 4; ++q) {            // quad q holds channels 8q..8q+7
            union { int4 qq; h2 hh[4]; } u;
#pragma unroll
            for (int e = 0; e < 4; ++e) {
                h2 v2;
                v2[0] = (_Float16)(b[8 * q + 2 * e]     * rs);
                v2[1] = (_Float16)(b[8 * q + 2 * e + 1] * rs);
                u.hh[e] = v2;
            }
            lds[h * 4 + (q ^ ((h >> 1) & 3))] = u.qq;   // bank swizzle
        }
    }
    __syncthreads();

    // ---------------- Phase 2: per-voxel dots + softmax --------------------
    const int lane = tid & 63;
    const int w    = tid >> 6;
    const int hi   = lane >> 5;          // channel half
    const int slot = lane & 31;
    const int ov   = w * 32 + slot;      // 0..191, tz-consecutive
    const int tz   = ov % Z_;
    const int txy  = ov / Z_;
    const int ty   = txy % TY_;
    const int tx   = txy / TY_;
    const int gx = x0 + tx, gy = y0 + ty, gz = tz;
    const int gm = (gx * Y_ + gy) * Z_ + gz;

    // own 16 raw f0 channels; cross-half norm reduce
    const float* p0 = f0 + (size_t)n * C_ * M_ + (size_t)hi * 16 * M_ + gm;
    float a[16];
    float s0 = 0.f;
#pragma unroll
    for (int i = 0; i < 16; ++i) {
        a[i] = p0[(size_t)i * M_];
        s0 = fmaf(a[i], a[i], s0);
    }
    s0 += __shfl_xor(s0, 32, 64);
    float rs0 = __expf(logit_scale[0]) / (sqrtf(s0) + 1e-7f);
    h2 A[8];
#pragma unroll
    for (int i = 0; i < 8; ++i) {
        h2 v;
        v[0] = (_Float16)(a[2 * i]     * rs0);
        v[1] = (_Float16)(a[2 * i + 1] * rs0);
        A[i] = v;
    }

    float S = 0.f, FX = 0.f, FY = 0.f, FZ = 0.f;
#pragma unroll
    for (int i = 0; i < 3; ++i)
#pragma unroll
    for (int j = 0; j < 3; ++j)
#pragma unroll
    for (int k = 0; k < 3; ++k) {
        bool val = (gx + i - 1 >= 0) & (gx + i - 1 < X_) &
                   (gy + j - 1 >= 0) & (gy + j - 1 < Y_) &
                   (gz + k - 1 >= 0) & (gz + k - 1 < Z_);
        int hz = min(max(tz + k - 1, 0), Z_ - 1);
        int v  = (tx + i) * (HY_ * Z_) + (ty + j) * Z_ + hz;
        union { int4 qq; h2 hh[4]; } B0, B1;
        int vx = (v >> 1) & 3;
        B0.qq = lds[v * 4 + ((2 * hi)     ^ vx)];
        B1.qq = lds[v * 4 + ((2 * hi + 1) ^ vx)];
        float d = 0.f;
#pragma unroll
        for (int e = 0; e < 4; ++e) d = dot2(A[e],     B0.hh[e], d);
#pragma unroll
        for (int e = 0; e < 4; ++e) d = dot2(A[4 + e], B1.hh[e], d);
        d += __shfl_xor(d, 32, 64);          // full 32-channel dot
        d = val ? d : 0.0f;                  // invalid -> logit exactly 0
        float e_ = __expf(d);                // bounded: |logit| <= 14.29
        S += e_;
        if (i == 0) FX -= e_; else if (i == 2) FX += e_;
        if (j == 0) FY -= e_; else if (j == 2) FY += e_;
        if (k == 0) FZ -= e_; else if (k == 2) FZ += e_;
    }

    if (hi == 0) {
        float inv = 1.0f / S;
        size_t ob = ((size_t)n * M_ + gm) * 3;
        out[ob + 0] = FX * inv;
        out[ob + 1] = FY * inv;
        out[ob + 2] = FZ * inv;
    }
}

extern "C" void kernel_launch(void* const* d_in, const int* in_sizes, int n_in,
                              void* d_out, int out_size, void* d_ws, size_t ws_size,
                              hipStream_t stream) {
    const float* f0 = (const float*)d_in[0];
    const float* f1 = (const float*)d_in[1];
    const float* ls = (const float*)d_in[3];
    float* out = (float*)d_out;

    const int blocks = NXT_ * NYT_ * N_;     // 576
    fused_kernel<<<blocks, THREADS_, 0, stream>>>(f0, f1, ls, out);
}